// Round 1
// baseline (315.564 us; speedup 1.0000x reference)
//
#include <hip/hip_runtime.h>

// B=4, N=8192, CIN=256, H=8, D=64, INNER=512, COUT=256. fp32 I/O.
// out[b] = u_x[b] @ Mb[b] + bo via collapsed per-batch 256x256 matrix.
// All GEMMs: split-bf16 MFMA (x = hi + lo, 3 mfma terms, rel err ~2^-16).
// Inputs pre-split to bf16 hi/lo ONCE (prep kernels).
// THIS ROUND: staging in kv_dots_kernel/out_kernel converted to
// wave-specialized __builtin_amdgcn_global_load_lds width=16 (async
// global->LDS, no VGPR round-trip, no ds_write). LDS buffers unpadded
// ([4 planes][128 rows][8 cols], 2048 B/plane) to satisfy the
// linear base+lane*16 destination requirement.

#define B_    4
#define N_    8192
#define CIN_  256
#define H_    8
#define D_    64
#define INNER_ 512
#define COUT_ 256
#define EPS_  1e-5f

typedef unsigned short ushort_t;
typedef unsigned int   uint_t;
typedef __attribute__((ext_vector_type(8))) short short8;
typedef __attribute__((ext_vector_type(4))) float f32x4;

__device__ __forceinline__ void split_bf16(float x, ushort_t& hi, ushort_t& lo) {
  const uint_t u = __float_as_uint(x);
  const uint_t hr = (u + 0x8000u) & 0xffff0000u;   // round-half-up to bf16
  hi = (ushort_t)(hr >> 16);
  const float l = x - __uint_as_float(hr);          // exact residual
  lo = (ushort_t)((__float_as_uint(l) + 0x8000u) >> 16);
}

__device__ __forceinline__ void cvt8(float4 x, float4 y, uint4& uh, uint4& ul) {
  const float v[8] = {x.x, x.y, x.z, x.w, y.x, y.y, y.z, y.w};
  ushort_t h[8], l[8];
#pragma unroll
  for (int j = 0; j < 8; j++) split_bf16(v[j], h[j], l[j]);
  uh = make_uint4(h[0] | ((uint_t)h[1] << 16), h[2] | ((uint_t)h[3] << 16),
                  h[4] | ((uint_t)h[5] << 16), h[6] | ((uint_t)h[7] << 16));
  ul = make_uint4(l[0] | ((uint_t)l[1] << 16), l[2] | ((uint_t)l[3] << 16),
                  l[4] | ((uint_t)l[5] << 16), l[6] | ((uint_t)l[7] << 16));
}

#define MFMA(A, Bv, C) __builtin_amdgcn_mfma_f32_16x16x32_bf16((A), (Bv), (C), 0, 0, 0)

// async 16B global->LDS; dst is wave-uniform base, HW writes lane l at +16*l.
__device__ __forceinline__ void gload_lds16(const ushort_t* g, char* l) {
  __builtin_amdgcn_global_load_lds(
      (const __attribute__((address_space(1))) void*)(const void*)g,
      (__attribute__((address_space(3))) void*)(void*)l, 16, 0, 0);
}

// ---------------------------------------------------------------------------
// Prep: split fp32 -> packed bf16 hi/lo global arrays.
// ---------------------------------------------------------------------------
__global__ __launch_bounds__(256) void prep_ux_kernel(
    const float* __restrict__ u_x, ushort_t* __restrict__ uxH,
    ushort_t* __restrict__ uxL)
{
  const size_t base = ((size_t)blockIdx.x * 256 + threadIdx.x) * 8;
  const float4 x = *(const float4*)(u_x + base);
  const float4 y = *(const float4*)(u_x + base + 4);
  uint4 uh, ul;
  cvt8(x, y, uh, ul);
  *(uint4*)(uxH + base) = uh;
  *(uint4*)(uxL + base) = ul;
}

__global__ __launch_bounds__(256) void prep_w_kernel(
    const float* __restrict__ Wk, const float* __restrict__ Wv,
    ushort_t* __restrict__ WkvH, ushort_t* __restrict__ WkvL)
{
  const size_t base = ((size_t)blockIdx.x * 256 + threadIdx.x) * 8;  // 0..262143
  const float* src = (base < 131072) ? (Wk + base) : (Wv + base - 131072);
  const float4 x = *(const float4*)(src);
  const float4 y = *(const float4*)(src + 4);
  uint4 uh, ul;
  cvt8(x, y, uh, ul);
  *(uint4*)(WkvH + base) = uh;
  *(uint4*)(WkvL + base) = ul;
}

// ---------------------------------------------------------------------------
// Kernel 1: per (chunk of 256 rows, h, b): 2 macro-tiles of 128 rows:
//   KV = u_x @ [Wk_h;Wv_h]^T (split-bf16 MFMA, global_load_lds staging)
//   InstanceNorm in-register (per-wave cols are exactly one K/V half)
//   transpose normalized bf16 hi/lo -> LDS, dots += Kt.Vt^T on MFMA
// atomicAdd 64x64 dots per (b,h) at end.
// LDS: union(staging 32768 B, Kt/Vt 4x9216 B) = 36864 B.
// Staging: wave w owns buffer w (Ah/Al/Bh/Bl); 8x gl_lds of 1 KiB per kc.
// gl_lds j -> LDS bytes [j*1024,...): plane j>>1, rows (j&1)*64+lane.
// ---------------------------------------------------------------------------
__global__ __launch_bounds__(256, 2) void kv_dots_kernel(
    const ushort_t* __restrict__ uxH, const ushort_t* __restrict__ uxL,
    const ushort_t* __restrict__ WkvH, const ushort_t* __restrict__ WkvL,
    float* __restrict__ dots)
{
  __shared__ __align__(16) char smem[36864];
  ushort_t (*Ah)[128][8] = (ushort_t(*)[128][8])(smem);
  ushort_t (*Al)[128][8] = (ushort_t(*)[128][8])(smem + 8192);
  ushort_t (*Bh)[128][8] = (ushort_t(*)[128][8])(smem + 16384);
  ushort_t (*Bl)[128][8] = (ushort_t(*)[128][8])(smem + 24576);
  ushort_t* KtH = (ushort_t*)(smem);            // [64][72]
  ushort_t* KtL = (ushort_t*)(smem + 9216);
  ushort_t* VtH = (ushort_t*)(smem + 18432);
  ushort_t* VtL = (ushort_t*)(smem + 27648);

  const int t = threadIdx.x;
  const int chunk = blockIdx.x, h = blockIdx.y, b = blockIdx.z;
  const int lane = t & 63, wave = t >> 6;
  const int q = lane >> 4, r = lane & 15;
  const int m0 = (wave >> 1) * 64, n0 = (wave & 1) * 64;
  const int dstripe = 16 * wave;

  // wave-specialized staging source. waves 0/1: A (uxH/uxL, mt-dependent);
  // waves 2/3: B (WkvH/WkvL; half 1 jumps to the V block at row 512).
  const size_t halfoff = (wave < 2) ? (size_t)(64 * CIN_) : (size_t)(512 * CIN_);
  char* lbase = smem + wave * 8192;
  const ushort_t* gB = ((wave == 3) ? WkvL : WkvH) + (size_t)(h * 64 + lane) * CIN_;

  f32x4 dacc[4];
#pragma unroll
  for (int j = 0; j < 4; j++) dacc[j] = (f32x4)0.f;

  for (int mt = 0; mt < 2; mt++) {
    const int r0 = chunk * 256 + mt * 128;
    const ushort_t* gsrc =
        (wave == 0) ? (uxH + ((size_t)(b * N_) + r0 + lane) * CIN_)
      : (wave == 1) ? (uxL + ((size_t)(b * N_) + r0 + lane) * CIN_)
      : gB;

    f32x4 acc[4][4];
#pragma unroll
    for (int i = 0; i < 4; i++)
#pragma unroll
      for (int j = 0; j < 4; j++) acc[i][j] = (f32x4)0.f;

    for (int kc = 0; kc < 8; kc++) {
      // async-stage 32 k-cols of A and B (hi+lo), 8 KiB per buffer
      const ushort_t* gk = gsrc + kc * 32;
#pragma unroll
      for (int j = 0; j < 8; j++)
        gload_lds16(gk + (size_t)(j & 1) * halfoff + (j >> 1) * 8,
                    lbase + j * 1024);
      __syncthreads();
      short8 ahf[4], alf[4];
#pragma unroll
      for (int mi = 0; mi < 4; mi++) {
        ahf[mi] = *(const short8*)&Ah[q][m0 + 16 * mi + r][0];
        alf[mi] = *(const short8*)&Al[q][m0 + 16 * mi + r][0];
      }
#pragma unroll
      for (int nj = 0; nj < 4; nj++) {
        const short8 bhv = *(const short8*)&Bh[q][n0 + 16 * nj + r][0];
        const short8 blv = *(const short8*)&Bl[q][n0 + 16 * nj + r][0];
#pragma unroll
        for (int mi = 0; mi < 4; mi++) {
          acc[mi][nj] = MFMA(ahf[mi], bhv, acc[mi][nj]);
          acc[mi][nj] = MFMA(alf[mi], bhv, acc[mi][nj]);
          acc[mi][nj] = MFMA(ahf[mi], blv, acc[mi][nj]);
        }
      }
      __syncthreads();
    }

    // ---- InstanceNorm in-register. Wave's 64 cols are one K/V half; row
    // (seq index) = m0 + 16mi + 4q + reg; stats over 64 cols = sum over nj
    // then over the 16 lanes of the quad.
    float mean[4][4], inv[4][4];
#pragma unroll
    for (int mi = 0; mi < 4; mi++)
#pragma unroll
      for (int reg = 0; reg < 4; reg++) {
        float rs = 0.f, rq = 0.f;
#pragma unroll
        for (int nj = 0; nj < 4; nj++) {
          const float v = acc[mi][nj][reg];
          rs += v;
          rq = fmaf(v, v, rq);
        }
#pragma unroll
        for (int msk = 1; msk < 16; msk <<= 1) {
          rs += __shfl_xor(rs, msk, 64);
          rq += __shfl_xor(rq, msk, 64);
        }
        const float m = rs * (1.f / 64.f);
        const float var = fmaxf(rq * (1.f / 64.f) - m * m, 0.f);
        mean[mi][reg] = m;
        inv[mi][reg] = rsqrtf(var + EPS_);
      }
#pragma unroll
    for (int mi = 0; mi < 4; mi++)
#pragma unroll
      for (int nj = 0; nj < 4; nj++)
#pragma unroll
        for (int reg = 0; reg < 4; reg++)
          acc[mi][nj][reg] = (acc[mi][nj][reg] - mean[mi][reg]) * inv[mi][reg];

    // ---- two 64-row halves: transpose to LDS (bf16 hi/lo), dots MFMA
    for (int p = 0; p < 2; p++) {
      if ((wave >> 1) == p) {
        ushort_t* Hd = (wave & 1) ? VtH : KtH;
        ushort_t* Ld = (wave & 1) ? VtL : KtL;
#pragma unroll
        for (int nj = 0; nj < 4; nj++) {
          const int d = 16 * nj + r;
#pragma unroll
          for (int mi = 0; mi < 4; mi++) {
            const int nb = 16 * mi + 4 * q;
            ushort_t hh[4], ll[4];
#pragma unroll
            for (int reg = 0; reg < 4; reg++)
              split_bf16(acc[mi][nj][reg], hh[reg], ll[reg]);
            uint2 ph, pl;
            ph.x = hh[0] | ((uint_t)hh[1] << 16);
            ph.y = hh[2] | ((uint_t)hh[3] << 16);
            pl.x = ll[0] | ((uint_t)ll[1] << 16);
            pl.y = ll[2] | ((uint_t)ll[3] << 16);
            *(uint2*)&Hd[d * 72 + nb] = ph;
            *(uint2*)&Ld[d * 72 + nb] = pl;
          }
        }
      }
      __syncthreads();
#pragma unroll
      for (int ks = 0; ks < 2; ks++) {
        const short8 aH = *(const short8*)&KtH[(dstripe + r) * 72 + ks * 32 + q * 8];
        const short8 aL = *(const short8*)&KtL[(dstripe + r) * 72 + ks * 32 + q * 8];
#pragma unroll
        for (int ej = 0; ej < 4; ej++) {
          const short8 bH = *(const short8*)&VtH[(16 * ej + r) * 72 + ks * 32 + q * 8];
          const short8 bL = *(const short8*)&VtL[(16 * ej + r) * 72 + ks * 32 + q * 8];
          dacc[ej] = MFMA(aH, bH, dacc[ej]);
          dacc[ej] = MFMA(aL, bH, dacc[ej]);
          dacc[ej] = MFMA(aH, bL, dacc[ej]);
        }
      }
      __syncthreads();
    }
  }

  float* dg = dots + ((size_t)(b * H_ + h)) * 4096;
#pragma unroll
  for (int ej = 0; ej < 4; ej++)
#pragma unroll
    for (int reg = 0; reg < 4; reg++)
      atomicAdd(&dg[(dstripe + 4 * q + reg) * 64 + 16 * ej + r], dacc[ej][reg]);
}

// ---------------------------------------------------------------------------
// Kernel 2a: S[b][hd][o] = sum_e dots[b,h,d,e] * Wo[o, h*64+e]
// ---------------------------------------------------------------------------
__global__ __launch_bounds__(256) void s_kernel(
    const float* __restrict__ dots, const float* __restrict__ Wo,
    float* __restrict__ S)
{
  const int blk = blockIdx.x;  // b*512 + hd
  const int b = blk >> 9, hd = blk & 511, h = hd >> 6;
  __shared__ float drow[64];
  const int t = threadIdx.x;
  if (t < 64) drow[t] = dots[((size_t)(b * H_ + h)) * 4096 + (hd & 63) * 64 + t];
  __syncthreads();
  const float* wp = Wo + (size_t)t * INNER_ + h * 64;
  float acc = 0.f;
#pragma unroll
  for (int e = 0; e < 64; e += 4) {
    const float4 w = *(const float4*)(wp + e);
    acc = fmaf(drow[e + 0], w.x, acc);
    acc = fmaf(drow[e + 1], w.y, acc);
    acc = fmaf(drow[e + 2], w.z, acc);
    acc = fmaf(drow[e + 3], w.w, acc);
  }
  S[((size_t)(b * INNER_) + hd) * COUT_ + t] = acc;
}

// ---------------------------------------------------------------------------
// Kernel 2b: partial Mb over hd-chunks of 128 (grid: 16 c-tiles x 4 b x 4 s)
// ---------------------------------------------------------------------------
__global__ __launch_bounds__(256) void mb_part_kernel(
    const float* __restrict__ Wq, const float* __restrict__ S,
    float* __restrict__ Mbp)
{
  __shared__ __align__(16) float wql[128][16];
  const int c0 = blockIdx.x * 16, b = blockIdx.y, s = blockIdx.z;
  const int t = threadIdx.x;
#pragma unroll
  for (int i = 0; i < 8; i++) {
    const int idx = i * 256 + t;  // 0..2047
    wql[idx >> 4][idx & 15] = Wq[(size_t)(s * 128 + (idx >> 4)) * CIN_ + c0 + (idx & 15)];
  }
  __syncthreads();
  float acc[16];
#pragma unroll
  for (int cp = 0; cp < 16; cp++) acc[cp] = 0.f;
  const float* sp = S + ((size_t)(b * INNER_) + s * 128) * COUT_ + t;
  for (int hd = 0; hd < 128; hd++) {
    const float sv = sp[(size_t)hd * COUT_];
#pragma unroll
    for (int g = 0; g < 4; g++) {
      const float4 w = *(const float4*)&wql[hd][g * 4];
      acc[g * 4 + 0] = fmaf(w.x, sv, acc[g * 4 + 0]);
      acc[g * 4 + 1] = fmaf(w.y, sv, acc[g * 4 + 1]);
      acc[g * 4 + 2] = fmaf(w.z, sv, acc[g * 4 + 2]);
      acc[g * 4 + 3] = fmaf(w.w, sv, acc[g * 4 + 3]);
    }
  }
#pragma unroll
  for (int cp = 0; cp < 16; cp++)
    Mbp[(((size_t)s * 4 + b) * CIN_ + c0 + cp) * COUT_ + t] = acc[cp];
}

// ---------------------------------------------------------------------------
// Kernel 2c: merge 4 partials, scale 1/N, split bf16, write transposed Mbt.
// ---------------------------------------------------------------------------
__global__ __launch_bounds__(256) void mb_merge_kernel(
    const float* __restrict__ Mbp, ushort_t* __restrict__ MbtH,
    ushort_t* __restrict__ MbtL)
{
  const int c0 = blockIdx.x * 16, b = blockIdx.y;
  const int o = threadIdx.x;
#pragma unroll
  for (int cp = 0; cp < 16; cp++) {
    const int c = c0 + cp;
    float v = 0.f;
#pragma unroll
    for (int s = 0; s < 4; s++)
      v += Mbp[(((size_t)s * 4 + b) * CIN_ + c) * COUT_ + o];
    v *= (1.0f / N_);
    ushort_t hi, lo;
    split_bf16(v, hi, lo);
    const size_t off = ((size_t)(b * COUT_) + o) * CIN_ + c;
    MbtH[off] = hi;
    MbtL[off] = lo;
  }
}

// ---------------------------------------------------------------------------
// Kernel 3: out[b,n,o] = sum_c u_x[b,n,c] * Mbt[o][c] + bo[o], split-bf16
// MFMA, 128x128 tile; global_load_lds staging (wave-specialized).
// ---------------------------------------------------------------------------
__global__ __launch_bounds__(256, 2) void out_kernel(
    const ushort_t* __restrict__ uxH, const ushort_t* __restrict__ uxL,
    const ushort_t* __restrict__ MbtH, const ushort_t* __restrict__ MbtL,
    const float* __restrict__ bo, float* __restrict__ out)
{
  __shared__ __align__(16) char smem[32768];
  ushort_t (*Ah)[128][8] = (ushort_t(*)[128][8])(smem);
  ushort_t (*Al)[128][8] = (ushort_t(*)[128][8])(smem + 8192);
  ushort_t (*Bh)[128][8] = (ushort_t(*)[128][8])(smem + 16384);
  ushort_t (*Bl)[128][8] = (ushort_t(*)[128][8])(smem + 24576);

  const int t = threadIdx.x;
  const int r0 = blockIdx.x * 128, o0 = blockIdx.y * 128, b = blockIdx.z;
  const int lane = t & 63, wave = t >> 6;
  const int q = lane >> 4, r = lane & 15;
  const int m0 = (wave >> 1) * 64, n0 = (wave & 1) * 64;

  char* lbase = smem + wave * 8192;
  const size_t halfoff = (size_t)(64 * CIN_);
  const ushort_t* gsrc =
      (wave == 0) ? (uxH + ((size_t)(b * N_) + r0 + lane) * CIN_)
    : (wave == 1) ? (uxL + ((size_t)(b * N_) + r0 + lane) * CIN_)
    : (wave == 2) ? (MbtH + ((size_t)(b * COUT_) + o0 + lane) * CIN_)
    :               (MbtL + ((size_t)(b * COUT_) + o0 + lane) * CIN_);

  f32x4 acc[4][4];
#pragma unroll
  for (int i = 0; i < 4; i++)
#pragma unroll
    for (int j = 0; j < 4; j++) acc[i][j] = (f32x4)0.f;

  for (int kc = 0; kc < 8; kc++) {
    const ushort_t* gk = gsrc + kc * 32;
#pragma unroll
    for (int j = 0; j < 8; j++)
      gload_lds16(gk + (size_t)(j & 1) * halfoff + (j >> 1) * 8,
                  lbase + j * 1024);
    __syncthreads();
    short8 ahf[4], alf[4];
#pragma unroll
    for (int mi = 0; mi < 4; mi++) {
      ahf[mi] = *(const short8*)&Ah[q][m0 + 16 * mi + r][0];
      alf[mi] = *(const short8*)&Al[q][m0 + 16 * mi + r][0];
    }
#pragma unroll
    for (int nj = 0; nj < 4; nj++) {
      const short8 bhv = *(const short8*)&Bh[q][n0 + 16 * nj + r][0];
      const short8 blv = *(const short8*)&Bl[q][n0 + 16 * nj + r][0];
#pragma unroll
      for (int mi = 0; mi < 4; mi++) {
        acc[mi][nj] = MFMA(ahf[mi], bhv, acc[mi][nj]);
        acc[mi][nj] = MFMA(alf[mi], bhv, acc[mi][nj]);
        acc[mi][nj] = MFMA(ahf[mi], blv, acc[mi][nj]);
      }
    }
    __syncthreads();
  }

  float bov[4];
#pragma unroll
  for (int nj = 0; nj < 4; nj++) bov[nj] = bo[o0 + n0 + 16 * nj + r];
#pragma unroll
  for (int mi = 0; mi < 4; mi++)
#pragma unroll
    for (int nj = 0; nj < 4; nj++) {
      const f32x4 v = acc[mi][nj];
#pragma unroll
      for (int reg = 0; reg < 4; reg++) {
        const int row = r0 + m0 + 16 * mi + q * 4 + reg;
        out[((size_t)(b * N_) + row) * COUT_ + o0 + n0 + 16 * nj + r] =
            v[reg] + bov[nj];
      }
    }
}

extern "C" void kernel_launch(void* const* d_in, const int* in_sizes, int n_in,
                              void* d_out, int out_size, void* d_ws, size_t ws_size,
                              hipStream_t stream) {
  const float* u_x = (const float*)d_in[0];
  // d_in[1] = pos_x (unused)
  const float* Wq = (const float*)d_in[2];
  const float* Wk = (const float*)d_in[3];
  const float* Wv = (const float*)d_in[4];
  const float* Wo = (const float*)d_in[5];
  const float* bo = (const float*)d_in[6];
  float* out = (float*)d_out;

  // ws layout
  ushort_t* uxH  = (ushort_t*)d_ws;        // 8388608
  ushort_t* uxL  = uxH + 8388608;          // 8388608
  ushort_t* WkvH = uxL + 8388608;          // 262144
  ushort_t* WkvL = WkvH + 262144;          // 262144
  ushort_t* MbtH = WkvL + 262144;          // 262144
  ushort_t* MbtL = MbtH + 262144;          // 262144
  float* dots = (float*)(MbtL + 262144);   // 131072 floats
  float* S    = dots + 131072;             // 524288 floats
  float* Mbp  = S + 524288;                // 1048576 floats

  prep_ux_kernel<<<4096, 256, 0, stream>>>(u_x, uxH, uxL);
  prep_w_kernel<<<128, 256, 0, stream>>>(Wk, Wv, WkvH, WkvL);
  hipMemsetAsync(dots, 0, 131072 * sizeof(float), stream);
  kv_dots_kernel<<<dim3(32, 8, 4), 256, 0, stream>>>(uxH, uxL, WkvH, WkvL, dots);
  s_kernel<<<2048, 256, 0, stream>>>(dots, Wo, S);
  mb_part_kernel<<<dim3(16, 4, 4), 256, 0, stream>>>(Wq, S, Mbp);
  mb_merge_kernel<<<dim3(16, 4), 256, 0, stream>>>(Mbp, MbtH, MbtL);
  out_kernel<<<dim3(64, 2, 4), 256, 0, stream>>>(uxH, uxL, MbtH, MbtL, bo, out);
}

// Round 2
// 293.650 us; speedup vs baseline: 1.0746x; 1.0746x over previous
//
#include <hip/hip_runtime.h>

// B=4, N=8192, CIN=256, H=8, D=64, INNER=512, COUT=256. fp32 I/O.
// out[b] = u_x[b] @ Mb[b] + bo via collapsed per-batch 256x256 matrix.
// All GEMMs: split-bf16 MFMA (x = hi + lo, 3 mfma terms, rel err ~2^-16).
// Inputs pre-split to bf16 hi/lo ONCE (prep kernels) so staging is pure copy.
// THIS ROUND: reverted the global_load_lds experiment (strided source made
// each gl_lds touch 64 cache lines -> VMEM-serialized; 88->161us regression).
// Instead: __launch_bounds__(256,4) on both MFMA kernels -> 4 blocks/CU
// (LDS 4x36864=147K <= 160K, VGPR capped at 128). Doubles resident waves so
// one block's staging/barrier drain hides under another block's MFMA.

#define B_    4
#define N_    8192
#define CIN_  256
#define H_    8
#define D_    64
#define INNER_ 512
#define COUT_ 256
#define EPS_  1e-5f

typedef unsigned short ushort_t;
typedef unsigned int   uint_t;
typedef __attribute__((ext_vector_type(8))) short short8;
typedef __attribute__((ext_vector_type(4))) float f32x4;

__device__ __forceinline__ void split_bf16(float x, ushort_t& hi, ushort_t& lo) {
  const uint_t u = __float_as_uint(x);
  const uint_t hr = (u + 0x8000u) & 0xffff0000u;   // round-half-up to bf16
  hi = (ushort_t)(hr >> 16);
  const float l = x - __uint_as_float(hr);          // exact residual
  lo = (ushort_t)((__float_as_uint(l) + 0x8000u) >> 16);
}

__device__ __forceinline__ void cvt8(float4 x, float4 y, uint4& uh, uint4& ul) {
  const float v[8] = {x.x, x.y, x.z, x.w, y.x, y.y, y.z, y.w};
  ushort_t h[8], l[8];
#pragma unroll
  for (int j = 0; j < 8; j++) split_bf16(v[j], h[j], l[j]);
  uh = make_uint4(h[0] | ((uint_t)h[1] << 16), h[2] | ((uint_t)h[3] << 16),
                  h[4] | ((uint_t)h[5] << 16), h[6] | ((uint_t)h[7] << 16));
  ul = make_uint4(l[0] | ((uint_t)l[1] << 16), l[2] | ((uint_t)l[3] << 16),
                  l[4] | ((uint_t)l[5] << 16), l[6] | ((uint_t)l[7] << 16));
}

#define MFMA(A, Bv, C) __builtin_amdgcn_mfma_f32_16x16x32_bf16((A), (Bv), (C), 0, 0, 0)

// ---------------------------------------------------------------------------
// Prep: split fp32 -> packed bf16 hi/lo global arrays.
// ---------------------------------------------------------------------------
__global__ __launch_bounds__(256) void prep_ux_kernel(
    const float* __restrict__ u_x, ushort_t* __restrict__ uxH,
    ushort_t* __restrict__ uxL)
{
  const size_t base = ((size_t)blockIdx.x * 256 + threadIdx.x) * 8;
  const float4 x = *(const float4*)(u_x + base);
  const float4 y = *(const float4*)(u_x + base + 4);
  uint4 uh, ul;
  cvt8(x, y, uh, ul);
  *(uint4*)(uxH + base) = uh;
  *(uint4*)(uxL + base) = ul;
}

__global__ __launch_bounds__(256) void prep_w_kernel(
    const float* __restrict__ Wk, const float* __restrict__ Wv,
    ushort_t* __restrict__ WkvH, ushort_t* __restrict__ WkvL)
{
  const size_t base = ((size_t)blockIdx.x * 256 + threadIdx.x) * 8;  // 0..262143
  const float* src = (base < 131072) ? (Wk + base) : (Wv + base - 131072);
  const float4 x = *(const float4*)(src);
  const float4 y = *(const float4*)(src + 4);
  uint4 uh, ul;
  cvt8(x, y, uh, ul);
  *(uint4*)(WkvH + base) = uh;
  *(uint4*)(WkvL + base) = ul;
}

// ---------------------------------------------------------------------------
// Kernel 1: per (chunk of 256 rows, h, b): 2 macro-tiles of 128 rows:
//   KV = u_x @ [Wk_h;Wv_h]^T (split-bf16 MFMA, pure-copy staging)
//   InstanceNorm in-register (per-wave cols are exactly one K/V half)
//   transpose normalized bf16 hi/lo -> LDS, dots += Kt.Vt^T on MFMA
// atomicAdd 64x64 dots per (b,h) at end.
// LDS: union(staging 33280 B, Kt/Vt 4x9216 B) = 36864 B.
// ---------------------------------------------------------------------------
__global__ __launch_bounds__(256, 4) void kv_dots_kernel(
    const ushort_t* __restrict__ uxH, const ushort_t* __restrict__ uxL,
    const ushort_t* __restrict__ WkvH, const ushort_t* __restrict__ WkvL,
    float* __restrict__ dots)
{
  __shared__ __align__(16) char smem[36864];
  ushort_t (*Ah)[130][8] = (ushort_t(*)[130][8])(smem);
  ushort_t (*Al)[130][8] = (ushort_t(*)[130][8])(smem + 8320);
  ushort_t (*Bh)[130][8] = (ushort_t(*)[130][8])(smem + 16640);
  ushort_t (*Bl)[130][8] = (ushort_t(*)[130][8])(smem + 24960);
  ushort_t* KtH = (ushort_t*)(smem);            // [64][72]
  ushort_t* KtL = (ushort_t*)(smem + 9216);
  ushort_t* VtH = (ushort_t*)(smem + 18432);
  ushort_t* VtL = (ushort_t*)(smem + 27648);

  const int t = threadIdx.x;
  const int chunk = blockIdx.x, h = blockIdx.y, b = blockIdx.z;
  const int lane = t & 63, wave = t >> 6;
  const int q = lane >> 4, r = lane & 15;
  const int m0 = (wave >> 1) * 64, n0 = (wave & 1) * 64;
  const int srow = t >> 1, scs = (t & 1) * 16, q0 = (t & 1) * 2;
  const int dstripe = 16 * wave;

  // weight row for this thread's B staging (fixed across macro-tiles)
  const int wr = (srow < 64) ? (h * 64 + srow) : (512 + h * 64 + srow - 64);
  const ushort_t* bgH = WkvH + (size_t)wr * CIN_ + scs;
  const ushort_t* bgL = WkvL + (size_t)wr * CIN_ + scs;

  f32x4 dacc[4];
#pragma unroll
  for (int j = 0; j < 4; j++) dacc[j] = (f32x4)0.f;

  for (int mt = 0; mt < 2; mt++) {
    const int r0 = chunk * 256 + mt * 128;
    const ushort_t* agH = uxH + ((size_t)(b * N_) + r0 + srow) * CIN_ + scs;
    const ushort_t* agL = uxL + ((size_t)(b * N_) + r0 + srow) * CIN_ + scs;

    f32x4 acc[4][4];
#pragma unroll
    for (int i = 0; i < 4; i++)
#pragma unroll
      for (int j = 0; j < 4; j++) acc[i][j] = (f32x4)0.f;

    for (int kc = 0; kc < 8; kc++) {
      // stage 32 k-cols (pure copies)
      *(uint4*)&Ah[q0][srow][0]     = *(const uint4*)(agH + kc * 32);
      *(uint4*)&Ah[q0 + 1][srow][0] = *(const uint4*)(agH + kc * 32 + 8);
      *(uint4*)&Al[q0][srow][0]     = *(const uint4*)(agL + kc * 32);
      *(uint4*)&Al[q0 + 1][srow][0] = *(const uint4*)(agL + kc * 32 + 8);
      *(uint4*)&Bh[q0][srow][0]     = *(const uint4*)(bgH + kc * 32);
      *(uint4*)&Bh[q0 + 1][srow][0] = *(const uint4*)(bgH + kc * 32 + 8);
      *(uint4*)&Bl[q0][srow][0]     = *(const uint4*)(bgL + kc * 32);
      *(uint4*)&Bl[q0 + 1][srow][0] = *(const uint4*)(bgL + kc * 32 + 8);
      __syncthreads();
      short8 ahf[4], alf[4];
#pragma unroll
      for (int mi = 0; mi < 4; mi++) {
        ahf[mi] = *(const short8*)&Ah[q][m0 + 16 * mi + r][0];
        alf[mi] = *(const short8*)&Al[q][m0 + 16 * mi + r][0];
      }
#pragma unroll
      for (int nj = 0; nj < 4; nj++) {
        const short8 bhv = *(const short8*)&Bh[q][n0 + 16 * nj + r][0];
        const short8 blv = *(const short8*)&Bl[q][n0 + 16 * nj + r][0];
#pragma unroll
        for (int mi = 0; mi < 4; mi++) {
          acc[mi][nj] = MFMA(ahf[mi], bhv, acc[mi][nj]);
          acc[mi][nj] = MFMA(alf[mi], bhv, acc[mi][nj]);
          acc[mi][nj] = MFMA(ahf[mi], blv, acc[mi][nj]);
        }
      }
      __syncthreads();
    }

    // ---- InstanceNorm in-register. Wave's 64 cols are one K/V half; row
    // (seq index) = m0 + 16mi + 4q + reg; stats over 64 cols = sum over nj
    // then over the 16 lanes of the quad.
    float mean[4][4], inv[4][4];
#pragma unroll
    for (int mi = 0; mi < 4; mi++)
#pragma unroll
      for (int reg = 0; reg < 4; reg++) {
        float rs = 0.f, rq = 0.f;
#pragma unroll
        for (int nj = 0; nj < 4; nj++) {
          const float v = acc[mi][nj][reg];
          rs += v;
          rq = fmaf(v, v, rq);
        }
#pragma unroll
        for (int msk = 1; msk < 16; msk <<= 1) {
          rs += __shfl_xor(rs, msk, 64);
          rq += __shfl_xor(rq, msk, 64);
        }
        const float m = rs * (1.f / 64.f);
        const float var = fmaxf(rq * (1.f / 64.f) - m * m, 0.f);
        mean[mi][reg] = m;
        inv[mi][reg] = rsqrtf(var + EPS_);
      }
#pragma unroll
    for (int mi = 0; mi < 4; mi++)
#pragma unroll
      for (int nj = 0; nj < 4; nj++)
#pragma unroll
        for (int reg = 0; reg < 4; reg++)
          acc[mi][nj][reg] = (acc[mi][nj][reg] - mean[mi][reg]) * inv[mi][reg];

    // ---- two 64-row halves: transpose to LDS (bf16 hi/lo), dots MFMA
    for (int p = 0; p < 2; p++) {
      if ((wave >> 1) == p) {
        ushort_t* Hd = (wave & 1) ? VtH : KtH;
        ushort_t* Ld = (wave & 1) ? VtL : KtL;
#pragma unroll
        for (int nj = 0; nj < 4; nj++) {
          const int d = 16 * nj + r;
#pragma unroll
          for (int mi = 0; mi < 4; mi++) {
            const int nb = 16 * mi + 4 * q;
            ushort_t hh[4], ll[4];
#pragma unroll
            for (int reg = 0; reg < 4; reg++)
              split_bf16(acc[mi][nj][reg], hh[reg], ll[reg]);
            uint2 ph, pl;
            ph.x = hh[0] | ((uint_t)hh[1] << 16);
            ph.y = hh[2] | ((uint_t)hh[3] << 16);
            pl.x = ll[0] | ((uint_t)ll[1] << 16);
            pl.y = ll[2] | ((uint_t)ll[3] << 16);
            *(uint2*)&Hd[d * 72 + nb] = ph;
            *(uint2*)&Ld[d * 72 + nb] = pl;
          }
        }
      }
      __syncthreads();
#pragma unroll
      for (int ks = 0; ks < 2; ks++) {
        const short8 aH = *(const short8*)&KtH[(dstripe + r) * 72 + ks * 32 + q * 8];
        const short8 aL = *(const short8*)&KtL[(dstripe + r) * 72 + ks * 32 + q * 8];
#pragma unroll
        for (int ej = 0; ej < 4; ej++) {
          const short8 bH = *(const short8*)&VtH[(16 * ej + r) * 72 + ks * 32 + q * 8];
          const short8 bL = *(const short8*)&VtL[(16 * ej + r) * 72 + ks * 32 + q * 8];
          dacc[ej] = MFMA(aH, bH, dacc[ej]);
          dacc[ej] = MFMA(aL, bH, dacc[ej]);
          dacc[ej] = MFMA(aH, bL, dacc[ej]);
        }
      }
      __syncthreads();
    }
  }

  float* dg = dots + ((size_t)(b * H_ + h)) * 4096;
#pragma unroll
  for (int ej = 0; ej < 4; ej++)
#pragma unroll
    for (int reg = 0; reg < 4; reg++)
      atomicAdd(&dg[(dstripe + 4 * q + reg) * 64 + 16 * ej + r], dacc[ej][reg]);
}

// ---------------------------------------------------------------------------
// Kernel 2a: S[b][hd][o] = sum_e dots[b,h,d,e] * Wo[o, h*64+e]
// ---------------------------------------------------------------------------
__global__ __launch_bounds__(256) void s_kernel(
    const float* __restrict__ dots, const float* __restrict__ Wo,
    float* __restrict__ S)
{
  const int blk = blockIdx.x;  // b*512 + hd
  const int b = blk >> 9, hd = blk & 511, h = hd >> 6;
  __shared__ float drow[64];
  const int t = threadIdx.x;
  if (t < 64) drow[t] = dots[((size_t)(b * H_ + h)) * 4096 + (hd & 63) * 64 + t];
  __syncthreads();
  const float* wp = Wo + (size_t)t * INNER_ + h * 64;
  float acc = 0.f;
#pragma unroll
  for (int e = 0; e < 64; e += 4) {
    const float4 w = *(const float4*)(wp + e);
    acc = fmaf(drow[e + 0], w.x, acc);
    acc = fmaf(drow[e + 1], w.y, acc);
    acc = fmaf(drow[e + 2], w.z, acc);
    acc = fmaf(drow[e + 3], w.w, acc);
  }
  S[((size_t)(b * INNER_) + hd) * COUT_ + t] = acc;
}

// ---------------------------------------------------------------------------
// Kernel 2b: partial Mb over hd-chunks of 128 (grid: 16 c-tiles x 4 b x 4 s)
// ---------------------------------------------------------------------------
__global__ __launch_bounds__(256) void mb_part_kernel(
    const float* __restrict__ Wq, const float* __restrict__ S,
    float* __restrict__ Mbp)
{
  __shared__ __align__(16) float wql[128][16];
  const int c0 = blockIdx.x * 16, b = blockIdx.y, s = blockIdx.z;
  const int t = threadIdx.x;
#pragma unroll
  for (int i = 0; i < 8; i++) {
    const int idx = i * 256 + t;  // 0..2047
    wql[idx >> 4][idx & 15] = Wq[(size_t)(s * 128 + (idx >> 4)) * CIN_ + c0 + (idx & 15)];
  }
  __syncthreads();
  float acc[16];
#pragma unroll
  for (int cp = 0; cp < 16; cp++) acc[cp] = 0.f;
  const float* sp = S + ((size_t)(b * INNER_) + s * 128) * COUT_ + t;
  for (int hd = 0; hd < 128; hd++) {
    const float sv = sp[(size_t)hd * COUT_];
#pragma unroll
    for (int g = 0; g < 4; g++) {
      const float4 w = *(const float4*)&wql[hd][g * 4];
      acc[g * 4 + 0] = fmaf(w.x, sv, acc[g * 4 + 0]);
      acc[g * 4 + 1] = fmaf(w.y, sv, acc[g * 4 + 1]);
      acc[g * 4 + 2] = fmaf(w.z, sv, acc[g * 4 + 2]);
      acc[g * 4 + 3] = fmaf(w.w, sv, acc[g * 4 + 3]);
    }
  }
#pragma unroll
  for (int cp = 0; cp < 16; cp++)
    Mbp[(((size_t)s * 4 + b) * CIN_ + c0 + cp) * COUT_ + t] = acc[cp];
}

// ---------------------------------------------------------------------------
// Kernel 2c: merge 4 partials, scale 1/N, split bf16, write transposed Mbt.
// ---------------------------------------------------------------------------
__global__ __launch_bounds__(256) void mb_merge_kernel(
    const float* __restrict__ Mbp, ushort_t* __restrict__ MbtH,
    ushort_t* __restrict__ MbtL)
{
  const int c0 = blockIdx.x * 16, b = blockIdx.y;
  const int o = threadIdx.x;
#pragma unroll
  for (int cp = 0; cp < 16; cp++) {
    const int c = c0 + cp;
    float v = 0.f;
#pragma unroll
    for (int s = 0; s < 4; s++)
      v += Mbp[(((size_t)s * 4 + b) * CIN_ + c) * COUT_ + o];
    v *= (1.0f / N_);
    ushort_t hi, lo;
    split_bf16(v, hi, lo);
    const size_t off = ((size_t)(b * COUT_) + o) * CIN_ + c;
    MbtH[off] = hi;
    MbtL[off] = lo;
  }
}

// ---------------------------------------------------------------------------
// Kernel 3: out[b,n,o] = sum_c u_x[b,n,c] * Mbt[o][c] + bo[o], split-bf16
// MFMA, 128x128 tile; all staging is pure copies.
// ---------------------------------------------------------------------------
__global__ __launch_bounds__(256, 4) void out_kernel(
    const ushort_t* __restrict__ uxH, const ushort_t* __restrict__ uxL,
    const ushort_t* __restrict__ MbtH, const ushort_t* __restrict__ MbtL,
    const float* __restrict__ bo, float* __restrict__ out)
{
  __shared__ __align__(16) char smem[33280];
  ushort_t (*Ah)[130][8] = (ushort_t(*)[130][8])(smem);
  ushort_t (*Al)[130][8] = (ushort_t(*)[130][8])(smem + 8320);
  ushort_t (*Bh)[130][8] = (ushort_t(*)[130][8])(smem + 16640);
  ushort_t (*Bl)[130][8] = (ushort_t(*)[130][8])(smem + 24960);

  const int t = threadIdx.x;
  const int r0 = blockIdx.x * 128, o0 = blockIdx.y * 128, b = blockIdx.z;
  const int lane = t & 63, wave = t >> 6;
  const int q = lane >> 4, r = lane & 15;
  const int m0 = (wave >> 1) * 64, n0 = (wave & 1) * 64;
  const int srow = t >> 1, scs = (t & 1) * 16, q0 = (t & 1) * 2;

  const ushort_t* agH = uxH + ((size_t)(b * N_) + r0 + srow) * CIN_ + scs;
  const ushort_t* agL = uxL + ((size_t)(b * N_) + r0 + srow) * CIN_ + scs;
  const ushort_t* bgH = MbtH + ((size_t)(b * COUT_) + o0 + srow) * CIN_ + scs;
  const ushort_t* bgL = MbtL + ((size_t)(b * COUT_) + o0 + srow) * CIN_ + scs;

  f32x4 acc[4][4];
#pragma unroll
  for (int i = 0; i < 4; i++)
#pragma unroll
    for (int j = 0; j < 4; j++) acc[i][j] = (f32x4)0.f;

  for (int kc = 0; kc < 8; kc++) {
    *(uint4*)&Ah[q0][srow][0]     = *(const uint4*)(agH + kc * 32);
    *(uint4*)&Ah[q0 + 1][srow][0] = *(const uint4*)(agH + kc * 32 + 8);
    *(uint4*)&Al[q0][srow][0]     = *(const uint4*)(agL + kc * 32);
    *(uint4*)&Al[q0 + 1][srow][0] = *(const uint4*)(agL + kc * 32 + 8);
    *(uint4*)&Bh[q0][srow][0]     = *(const uint4*)(bgH + kc * 32);
    *(uint4*)&Bh[q0 + 1][srow][0] = *(const uint4*)(bgH + kc * 32 + 8);
    *(uint4*)&Bl[q0][srow][0]     = *(const uint4*)(bgL + kc * 32);
    *(uint4*)&Bl[q0 + 1][srow][0] = *(const uint4*)(bgL + kc * 32 + 8);
    __syncthreads();
    short8 ahf[4], alf[4];
#pragma unroll
    for (int mi = 0; mi < 4; mi++) {
      ahf[mi] = *(const short8*)&Ah[q][m0 + 16 * mi + r][0];
      alf[mi] = *(const short8*)&Al[q][m0 + 16 * mi + r][0];
    }
#pragma unroll
    for (int nj = 0; nj < 4; nj++) {
      const short8 bhv = *(const short8*)&Bh[q][n0 + 16 * nj + r][0];
      const short8 blv = *(const short8*)&Bl[q][n0 + 16 * nj + r][0];
#pragma unroll
      for (int mi = 0; mi < 4; mi++) {
        acc[mi][nj] = MFMA(ahf[mi], bhv, acc[mi][nj]);
        acc[mi][nj] = MFMA(alf[mi], bhv, acc[mi][nj]);
        acc[mi][nj] = MFMA(ahf[mi], blv, acc[mi][nj]);
      }
    }
    __syncthreads();
  }

  float bov[4];
#pragma unroll
  for (int nj = 0; nj < 4; nj++) bov[nj] = bo[o0 + n0 + 16 * nj + r];
#pragma unroll
  for (int mi = 0; mi < 4; mi++)
#pragma unroll
    for (int nj = 0; nj < 4; nj++) {
      const f32x4 v = acc[mi][nj];
#pragma unroll
      for (int reg = 0; reg < 4; reg++) {
        const int row = r0 + m0 + 16 * mi + q * 4 + reg;
        out[((size_t)(b * N_) + row) * COUT_ + o0 + n0 + 16 * nj + r] =
            v[reg] + bov[nj];
      }
    }
}

extern "C" void kernel_launch(void* const* d_in, const int* in_sizes, int n_in,
                              void* d_out, int out_size, void* d_ws, size_t ws_size,
                              hipStream_t stream) {
  const float* u_x = (const float*)d_in[0];
  // d_in[1] = pos_x (unused)
  const float* Wq = (const float*)d_in[2];
  const float* Wk = (const float*)d_in[3];
  const float* Wv = (const float*)d_in[4];
  const float* Wo = (const float*)d_in[5];
  const float* bo = (const float*)d_in[6];
  float* out = (float*)d_out;

  // ws layout
  ushort_t* uxH  = (ushort_t*)d_ws;        // 8388608
  ushort_t* uxL  = uxH + 8388608;          // 8388608
  ushort_t* WkvH = uxL + 8388608;          // 262144
  ushort_t* WkvL = WkvH + 262144;          // 262144
  ushort_t* MbtH = WkvL + 262144;          // 262144
  ushort_t* MbtL = MbtH + 262144;          // 262144
  float* dots = (float*)(MbtL + 262144);   // 131072 floats
  float* S    = dots + 131072;             // 524288 floats
  float* Mbp  = S + 524288;                // 1048576 floats

  prep_ux_kernel<<<4096, 256, 0, stream>>>(u_x, uxH, uxL);
  prep_w_kernel<<<128, 256, 0, stream>>>(Wk, Wv, WkvH, WkvL);
  hipMemsetAsync(dots, 0, 131072 * sizeof(float), stream);
  kv_dots_kernel<<<dim3(32, 8, 4), 256, 0, stream>>>(uxH, uxL, WkvH, WkvL, dots);
  s_kernel<<<2048, 256, 0, stream>>>(dots, Wo, S);
  mb_part_kernel<<<dim3(16, 4, 4), 256, 0, stream>>>(Wq, S, Mbp);
  mb_merge_kernel<<<dim3(16, 4), 256, 0, stream>>>(Mbp, MbtH, MbtL);
  out_kernel<<<dim3(64, 2, 4), 256, 0, stream>>>(uxH, uxL, MbtH, MbtL, bo, out);
}

// Round 3
// 235.562 us; speedup vs baseline: 1.3396x; 1.2466x over previous
//
#include <hip/hip_runtime.h>

// B=4, N=8192, CIN=256, H=8, D=64, INNER=512, COUT=256. fp32 I/O.
// out[b] = u_x[b] @ Mb[b] + bo via collapsed per-batch 256x256 matrix.
// All GEMMs: split-bf16 MFMA (x = hi + lo, 3 mfma terms, rel err ~2^-16).
// THIS ROUND: fragment-tiled global layout. prep kernels write uxH/uxL,
// WkvH/WkvL, MbtH/MbtL as 16x32 MFMA tiles stored lane-major (64 lanes x
// 16 B = 1 KiB per tile, exactly the A/B fragment order). GEMM phases read
// fragments DIRECTLY from global (one dwordx4 per frag) -> no LDS staging,
// no ds_write/ds_read, ZERO barriers in GEMM (out_kernel: zero total).
// Compiler can pipeline the K-loop freely; staging bank conflicts gone.
// Round-2 lesson: acc[4][4] (64 AGPRs) + ~120 VGPRs = ~184 unified regs;
// launch_bounds(256,4) forced spills (FETCH 20->137MB). Keep (256,2).

#define B_    4
#define N_    8192
#define CIN_  256
#define H_    8
#define D_    64
#define INNER_ 512
#define COUT_ 256
#define EPS_  1e-5f

typedef unsigned short ushort_t;
typedef unsigned int   uint_t;
typedef __attribute__((ext_vector_type(8))) short short8;
typedef __attribute__((ext_vector_type(4))) float f32x4;

__device__ __forceinline__ void split_bf16(float x, ushort_t& hi, ushort_t& lo) {
  const uint_t u = __float_as_uint(x);
  const uint_t hr = (u + 0x8000u) & 0xffff0000u;   // round-half-up to bf16
  hi = (ushort_t)(hr >> 16);
  const float l = x - __uint_as_float(hr);          // exact residual
  lo = (ushort_t)((__float_as_uint(l) + 0x8000u) >> 16);
}

__device__ __forceinline__ void cvt8(float4 x, float4 y, uint4& uh, uint4& ul) {
  const float v[8] = {x.x, x.y, x.z, x.w, y.x, y.y, y.z, y.w};
  ushort_t h[8], l[8];
#pragma unroll
  for (int j = 0; j < 8; j++) split_bf16(v[j], h[j], l[j]);
  uh = make_uint4(h[0] | ((uint_t)h[1] << 16), h[2] | ((uint_t)h[3] << 16),
                  h[4] | ((uint_t)h[5] << 16), h[6] | ((uint_t)h[7] << 16));
  ul = make_uint4(l[0] | ((uint_t)l[1] << 16), l[2] | ((uint_t)l[3] << 16),
                  l[4] | ((uint_t)l[5] << 16), l[6] | ((uint_t)l[7] << 16));
}

#define MFMA(A, Bv, C) __builtin_amdgcn_mfma_f32_16x16x32_bf16((A), (Bv), (C), 0, 0, 0)

// Fragment-tiled layout: element (row n, col c) of a [rows][256] matrix lives
// in tile (nt=n>>4, kt=c>>5), lane = (n&15) | (((c>>3)&3)<<4), elem = c&7.
// Tile = 64 lanes x 8 ushorts = 1 KiB, tiles ordered [nt][kt].

// ---------------------------------------------------------------------------
// Prep: split fp32 -> fragment-tiled bf16 hi/lo arrays.
// ---------------------------------------------------------------------------
__global__ __launch_bounds__(256) void prep_ux_kernel(
    const float* __restrict__ u_x, ushort_t* __restrict__ uxH,
    ushort_t* __restrict__ uxL)
{
  const uint_t tid = blockIdx.x * 256 + threadIdx.x;
  const size_t base = (size_t)tid * 8;
  const float4 x = *(const float4*)(u_x + base);
  const float4 y = *(const float4*)(u_x + base + 4);
  uint4 uh, ul;
  cvt8(x, y, uh, ul);
  const uint_t g = tid >> 5;            // b*8192 + n
  const uint_t c0 = (tid & 31) * 8;
  const uint_t b = g >> 13, n = g & 8191;
  const uint_t nt = n >> 4, kt = c0 >> 5, qq = (c0 >> 3) & 3;
  const uint_t lanei = (n & 15) | (qq << 4);
  const size_t dst = ((((size_t)b * 512 + nt) * 8 + kt) * 64 + lanei) * 8;
  *(uint4*)(uxH + dst) = uh;
  *(uint4*)(uxL + dst) = ul;
}

__global__ __launch_bounds__(256) void prep_w_kernel(
    const float* __restrict__ Wk, const float* __restrict__ Wv,
    ushort_t* __restrict__ WkvH, ushort_t* __restrict__ WkvL)
{
  const uint_t tid = blockIdx.x * 256 + threadIdx.x;  // 0..32767
  const uint_t rr = tid >> 5;            // kv row 0..1023 (K: 0..511, V: 512..)
  const uint_t c0 = (tid & 31) * 8;
  const float* src = (rr < 512) ? (Wk + (size_t)rr * CIN_ + c0)
                                : (Wv + (size_t)(rr - 512) * CIN_ + c0);
  const float4 x = *(const float4*)(src);
  const float4 y = *(const float4*)(src + 4);
  uint4 uh, ul;
  cvt8(x, y, uh, ul);
  const uint_t kt = c0 >> 5, qq = (c0 >> 3) & 3;
  const uint_t lanei = (rr & 15) | (qq << 4);
  const size_t dst = (((size_t)(rr >> 4) * 8 + kt) * 64 + lanei) * 8;
  *(uint4*)(WkvH + dst) = uh;
  *(uint4*)(WkvL + dst) = ul;
}

// ---------------------------------------------------------------------------
// Kernel 1: per (chunk of 256 rows, h, b): 2 macro-tiles of 128 rows:
//   KV = u_x @ [Wk_h;Wv_h]^T : frags loaded directly from tiled global,
//   no LDS, no barriers. InstanceNorm in-register. Then transpose
//   normalized bf16 hi/lo -> LDS, dots += Kt.Vt^T on MFMA.
// atomicAdd 64x64 dots per (b,h) at end. LDS: 4x9216 = 36864 B (Kt/Vt only).
// ---------------------------------------------------------------------------
__global__ __launch_bounds__(256, 2) void kv_dots_kernel(
    const ushort_t* __restrict__ uxH, const ushort_t* __restrict__ uxL,
    const ushort_t* __restrict__ WkvH, const ushort_t* __restrict__ WkvL,
    float* __restrict__ dots)
{
  __shared__ __align__(16) char smem[36864];
  ushort_t* KtH = (ushort_t*)(smem);            // [64][72]
  ushort_t* KtL = (ushort_t*)(smem + 9216);
  ushort_t* VtH = (ushort_t*)(smem + 18432);
  ushort_t* VtL = (ushort_t*)(smem + 27648);

  const int t = threadIdx.x;
  const int chunk = blockIdx.x, h = blockIdx.y, b = blockIdx.z;
  const int lane = t & 63, wave = t >> 6;
  const int q = lane >> 4, r = lane & 15;
  const int m0 = (wave >> 1) * 64, n0 = (wave & 1) * 64;
  const int dstripe = 16 * wave;
  const size_t laneoff = (size_t)lane * 8;

  // B tiles (weights) for this wave: K-half rows h*64.. -> tiles h*4+nj;
  // V-half rows 512+h*64.. -> tiles 32+h*4+nj.
  const int rtB0 = ((wave & 1) ? 32 : 0) + h * 4;

  f32x4 dacc[4];
#pragma unroll
  for (int j = 0; j < 4; j++) dacc[j] = (f32x4)0.f;

  for (int mt = 0; mt < 2; mt++) {
    const int nt0 = chunk * 16 + mt * 8 + (m0 >> 4);

    f32x4 acc[4][4];
#pragma unroll
    for (int i = 0; i < 4; i++)
#pragma unroll
      for (int j = 0; j < 4; j++) acc[i][j] = (f32x4)0.f;

    for (int kc = 0; kc < 8; kc++) {
      short8 ahf[4], alf[4];
#pragma unroll
      for (int mi = 0; mi < 4; mi++) {
        const size_t toff =
            (((size_t)b * 512 + nt0 + mi) * 8 + kc) * 512 + laneoff;
        ahf[mi] = *(const short8*)(uxH + toff);
        alf[mi] = *(const short8*)(uxL + toff);
      }
#pragma unroll
      for (int nj = 0; nj < 4; nj++) {
        const size_t boff = ((size_t)(rtB0 + nj) * 8 + kc) * 512 + laneoff;
        const short8 bhv = *(const short8*)(WkvH + boff);
        const short8 blv = *(const short8*)(WkvL + boff);
#pragma unroll
        for (int mi = 0; mi < 4; mi++) {
          acc[mi][nj] = MFMA(ahf[mi], bhv, acc[mi][nj]);
          acc[mi][nj] = MFMA(alf[mi], bhv, acc[mi][nj]);
          acc[mi][nj] = MFMA(ahf[mi], blv, acc[mi][nj]);
        }
      }
    }

    // ---- InstanceNorm in-register. Wave's 64 cols are one K/V half; row
    // (seq index) = m0 + 16mi + 4q + reg; stats over 64 cols = sum over nj
    // then over the 16 lanes of the quad.
    float mean[4][4], inv[4][4];
#pragma unroll
    for (int mi = 0; mi < 4; mi++)
#pragma unroll
      for (int reg = 0; reg < 4; reg++) {
        float rs = 0.f, rq = 0.f;
#pragma unroll
        for (int nj = 0; nj < 4; nj++) {
          const float v = acc[mi][nj][reg];
          rs += v;
          rq = fmaf(v, v, rq);
        }
#pragma unroll
        for (int msk = 1; msk < 16; msk <<= 1) {
          rs += __shfl_xor(rs, msk, 64);
          rq += __shfl_xor(rq, msk, 64);
        }
        const float m = rs * (1.f / 64.f);
        const float var = fmaxf(rq * (1.f / 64.f) - m * m, 0.f);
        mean[mi][reg] = m;
        inv[mi][reg] = rsqrtf(var + EPS_);
      }
#pragma unroll
    for (int mi = 0; mi < 4; mi++)
#pragma unroll
      for (int nj = 0; nj < 4; nj++)
#pragma unroll
        for (int reg = 0; reg < 4; reg++)
          acc[mi][nj][reg] = (acc[mi][nj][reg] - mean[mi][reg]) * inv[mi][reg];

    // ---- two 64-row halves: transpose to LDS (bf16 hi/lo), dots MFMA
    for (int p = 0; p < 2; p++) {
      if ((wave >> 1) == p) {
        ushort_t* Hd = (wave & 1) ? VtH : KtH;
        ushort_t* Ld = (wave & 1) ? VtL : KtL;
#pragma unroll
        for (int nj = 0; nj < 4; nj++) {
          const int d = 16 * nj + r;
#pragma unroll
          for (int mi = 0; mi < 4; mi++) {
            const int nb = 16 * mi + 4 * q;
            ushort_t hh[4], ll[4];
#pragma unroll
            for (int reg = 0; reg < 4; reg++)
              split_bf16(acc[mi][nj][reg], hh[reg], ll[reg]);
            uint2 ph, pl;
            ph.x = hh[0] | ((uint_t)hh[1] << 16);
            ph.y = hh[2] | ((uint_t)hh[3] << 16);
            pl.x = ll[0] | ((uint_t)ll[1] << 16);
            pl.y = ll[2] | ((uint_t)ll[3] << 16);
            *(uint2*)&Hd[d * 72 + nb] = ph;
            *(uint2*)&Ld[d * 72 + nb] = pl;
          }
        }
      }
      __syncthreads();
#pragma unroll
      for (int ks = 0; ks < 2; ks++) {
        const short8 aH = *(const short8*)&KtH[(dstripe + r) * 72 + ks * 32 + q * 8];
        const short8 aL = *(const short8*)&KtL[(dstripe + r) * 72 + ks * 32 + q * 8];
#pragma unroll
        for (int ej = 0; ej < 4; ej++) {
          const short8 bH = *(const short8*)&VtH[(16 * ej + r) * 72 + ks * 32 + q * 8];
          const short8 bL = *(const short8*)&VtL[(16 * ej + r) * 72 + ks * 32 + q * 8];
          dacc[ej] = MFMA(aH, bH, dacc[ej]);
          dacc[ej] = MFMA(aL, bH, dacc[ej]);
          dacc[ej] = MFMA(aH, bL, dacc[ej]);
        }
      }
      __syncthreads();
    }
  }

  float* dg = dots + ((size_t)(b * H_ + h)) * 4096;
#pragma unroll
  for (int ej = 0; ej < 4; ej++)
#pragma unroll
    for (int reg = 0; reg < 4; reg++)
      atomicAdd(&dg[(dstripe + 4 * q + reg) * 64 + 16 * ej + r], dacc[ej][reg]);
}

// ---------------------------------------------------------------------------
// Kernel 2a: S[b][hd][o] = sum_e dots[b,h,d,e] * Wo[o, h*64+e]
// ---------------------------------------------------------------------------
__global__ __launch_bounds__(256) void s_kernel(
    const float* __restrict__ dots, const float* __restrict__ Wo,
    float* __restrict__ S)
{
  const int blk = blockIdx.x;  // b*512 + hd
  const int b = blk >> 9, hd = blk & 511, h = hd >> 6;
  __shared__ float drow[64];
  const int t = threadIdx.x;
  if (t < 64) drow[t] = dots[((size_t)(b * H_ + h)) * 4096 + (hd & 63) * 64 + t];
  __syncthreads();
  const float* wp = Wo + (size_t)t * INNER_ + h * 64;
  float acc = 0.f;
#pragma unroll
  for (int e = 0; e < 64; e += 4) {
    const float4 w = *(const float4*)(wp + e);
    acc = fmaf(drow[e + 0], w.x, acc);
    acc = fmaf(drow[e + 1], w.y, acc);
    acc = fmaf(drow[e + 2], w.z, acc);
    acc = fmaf(drow[e + 3], w.w, acc);
  }
  S[((size_t)(b * INNER_) + hd) * COUT_ + t] = acc;
}

// ---------------------------------------------------------------------------
// Kernel 2b: partial Mb over hd-chunks of 128 (grid: 16 c-tiles x 4 b x 4 s)
// ---------------------------------------------------------------------------
__global__ __launch_bounds__(256) void mb_part_kernel(
    const float* __restrict__ Wq, const float* __restrict__ S,
    float* __restrict__ Mbp)
{
  __shared__ __align__(16) float wql[128][16];
  const int c0 = blockIdx.x * 16, b = blockIdx.y, s = blockIdx.z;
  const int t = threadIdx.x;
#pragma unroll
  for (int i = 0; i < 8; i++) {
    const int idx = i * 256 + t;  // 0..2047
    wql[idx >> 4][idx & 15] = Wq[(size_t)(s * 128 + (idx >> 4)) * CIN_ + c0 + (idx & 15)];
  }
  __syncthreads();
  float acc[16];
#pragma unroll
  for (int cp = 0; cp < 16; cp++) acc[cp] = 0.f;
  const float* sp = S + ((size_t)(b * INNER_) + s * 128) * COUT_ + t;
  for (int hd = 0; hd < 128; hd++) {
    const float sv = sp[(size_t)hd * COUT_];
#pragma unroll
    for (int g = 0; g < 4; g++) {
      const float4 w = *(const float4*)&wql[hd][g * 4];
      acc[g * 4 + 0] = fmaf(w.x, sv, acc[g * 4 + 0]);
      acc[g * 4 + 1] = fmaf(w.y, sv, acc[g * 4 + 1]);
      acc[g * 4 + 2] = fmaf(w.z, sv, acc[g * 4 + 2]);
      acc[g * 4 + 3] = fmaf(w.w, sv, acc[g * 4 + 3]);
    }
  }
#pragma unroll
  for (int cp = 0; cp < 16; cp++)
    Mbp[(((size_t)s * 4 + b) * CIN_ + c0 + cp) * COUT_ + t] = acc[cp];
}

// ---------------------------------------------------------------------------
// Kernel 2c: merge 4 partials, scale 1/N, split bf16, write fragment-tiled
// Mbt (o-row-tiled over CIN, same tiling as uxH).
// ---------------------------------------------------------------------------
__global__ __launch_bounds__(256) void mb_merge_kernel(
    const float* __restrict__ Mbp, ushort_t* __restrict__ MbtH,
    ushort_t* __restrict__ MbtL)
{
  const int c0 = blockIdx.x * 16, b = blockIdx.y;
  const int o = threadIdx.x;
#pragma unroll
  for (int cp = 0; cp < 16; cp++) {
    const int c = c0 + cp;
    float v = 0.f;
#pragma unroll
    for (int s = 0; s < 4; s++)
      v += Mbp[(((size_t)s * 4 + b) * CIN_ + c) * COUT_ + o];
    v *= (1.0f / N_);
    ushort_t hi, lo;
    split_bf16(v, hi, lo);
    const uint_t kt = c >> 5, qq = (c >> 3) & 3;
    const uint_t lanei = (o & 15) | (qq << 4);
    const size_t off =
        ((((size_t)b * 16 + (o >> 4)) * 8 + kt) * 64 + lanei) * 8 + (c & 7);
    MbtH[off] = hi;
    MbtL[off] = lo;
  }
}

// ---------------------------------------------------------------------------
// Kernel 3: out[b,n,o] = sum_c u_x[b,n,c] * Mbt[o][c] + bo[o], split-bf16
// MFMA, 128x128 tile; frags direct from tiled global. No LDS, no barriers.
// ---------------------------------------------------------------------------
__global__ __launch_bounds__(256, 2) void out_kernel(
    const ushort_t* __restrict__ uxH, const ushort_t* __restrict__ uxL,
    const ushort_t* __restrict__ MbtH, const ushort_t* __restrict__ MbtL,
    const float* __restrict__ bo, float* __restrict__ out)
{
  const int t = threadIdx.x;
  const int r0 = blockIdx.x * 128, o0 = blockIdx.y * 128, b = blockIdx.z;
  const int lane = t & 63, wave = t >> 6;
  const int q = lane >> 4, r = lane & 15;
  const int m0 = (wave >> 1) * 64, n0 = (wave & 1) * 64;
  const size_t laneoff = (size_t)lane * 8;

  const int nt0 = (r0 + m0) >> 4;
  const int ot0 = (o0 + n0) >> 4;

  f32x4 acc[4][4];
#pragma unroll
  for (int i = 0; i < 4; i++)
#pragma unroll
    for (int j = 0; j < 4; j++) acc[i][j] = (f32x4)0.f;

  for (int kc = 0; kc < 8; kc++) {
    short8 ahf[4], alf[4];
#pragma unroll
    for (int mi = 0; mi < 4; mi++) {
      const size_t toff =
          (((size_t)b * 512 + nt0 + mi) * 8 + kc) * 512 + laneoff;
      ahf[mi] = *(const short8*)(uxH + toff);
      alf[mi] = *(const short8*)(uxL + toff);
    }
#pragma unroll
    for (int nj = 0; nj < 4; nj++) {
      const size_t boff =
          (((size_t)b * 16 + ot0 + nj) * 8 + kc) * 512 + laneoff;
      const short8 bhv = *(const short8*)(MbtH + boff);
      const short8 blv = *(const short8*)(MbtL + boff);
#pragma unroll
      for (int mi = 0; mi < 4; mi++) {
        acc[mi][nj] = MFMA(ahf[mi], bhv, acc[mi][nj]);
        acc[mi][nj] = MFMA(alf[mi], bhv, acc[mi][nj]);
        acc[mi][nj] = MFMA(ahf[mi], blv, acc[mi][nj]);
      }
    }
  }

  float bov[4];
#pragma unroll
  for (int nj = 0; nj < 4; nj++) bov[nj] = bo[o0 + n0 + 16 * nj + r];
#pragma unroll
  for (int mi = 0; mi < 4; mi++)
#pragma unroll
    for (int nj = 0; nj < 4; nj++) {
      const f32x4 v = acc[mi][nj];
#pragma unroll
      for (int reg = 0; reg < 4; reg++) {
        const int row = r0 + m0 + 16 * mi + q * 4 + reg;
        out[((size_t)(b * N_) + row) * COUT_ + o0 + n0 + 16 * nj + r] =
            v[reg] + bov[nj];
      }
    }
}

extern "C" void kernel_launch(void* const* d_in, const int* in_sizes, int n_in,
                              void* d_out, int out_size, void* d_ws, size_t ws_size,
                              hipStream_t stream) {
  const float* u_x = (const float*)d_in[0];
  // d_in[1] = pos_x (unused)
  const float* Wq = (const float*)d_in[2];
  const float* Wk = (const float*)d_in[3];
  const float* Wv = (const float*)d_in[4];
  const float* Wo = (const float*)d_in[5];
  const float* bo = (const float*)d_in[6];
  float* out = (float*)d_out;

  // ws layout
  ushort_t* uxH  = (ushort_t*)d_ws;        // 8388608
  ushort_t* uxL  = uxH + 8388608;          // 8388608
  ushort_t* WkvH = uxL + 8388608;          // 262144
  ushort_t* WkvL = WkvH + 262144;          // 262144
  ushort_t* MbtH = WkvL + 262144;          // 262144
  ushort_t* MbtL = MbtH + 262144;          // 262144
  float* dots = (float*)(MbtL + 262144);   // 131072 floats
  float* S    = dots + 131072;             // 524288 floats
  float* Mbp  = S + 524288;                // 1048576 floats

  prep_ux_kernel<<<4096, 256, 0, stream>>>(u_x, uxH, uxL);
  prep_w_kernel<<<128, 256, 0, stream>>>(Wk, Wv, WkvH, WkvL);
  hipMemsetAsync(dots, 0, 131072 * sizeof(float), stream);
  kv_dots_kernel<<<dim3(32, 8, 4), 256, 0, stream>>>(uxH, uxL, WkvH, WkvL, dots);
  s_kernel<<<2048, 256, 0, stream>>>(dots, Wo, S);
  mb_part_kernel<<<dim3(16, 4, 4), 256, 0, stream>>>(Wq, S, Mbp);
  mb_merge_kernel<<<dim3(16, 4), 256, 0, stream>>>(Mbp, MbtH, MbtL);
  out_kernel<<<dim3(64, 2, 4), 256, 0, stream>>>(uxH, uxL, MbtH, MbtL, bo, out);
}